// Round 1
// baseline (4896.983 us; speedup 1.0000x reference)
//
#include <hip/hip_runtime.h>
#include <hip/hip_bf16.h>
#include <math.h>

#define DIM 512
#define VOCAB 10000
#define DEPTH 3
#define DSTATE 16
#define DCONV 4
#define DINNER 1024
#define DTRANK 32
#define BATCH 4
#define SEQ 1024
#define CTX 98
#define HEADS 8
#define DH 64
#define NTOK (BATCH*SEQ)   // 4096

__device__ __forceinline__ float sigmoidf_(float x){ return 1.f/(1.f+__expf(-x)); }

// ---------------------------------------------------------------- embedding
__global__ __launch_bounds__(128)
void embed_kernel(const int* __restrict__ x,
                  const float* __restrict__ tok_emb,
                  const float* __restrict__ pos_emb,
                  float* __restrict__ h)
{
    int row = blockIdx.x;            // 0..4095 = b*SEQ + l
    int l = row & (SEQ-1);
    int tok = x[row];
    const float4* te = (const float4*)(tok_emb + (size_t)tok*DIM);
    const float4* pe = (const float4*)(pos_emb + (size_t)l*DIM);
    float4* hp = (float4*)(h + (size_t)row*DIM);
    int i = threadIdx.x;             // DIM/4 = 128
    float4 a = te[i], b = pe[i];
    hp[i] = make_float4(a.x+b.x, a.y+b.y, a.z+b.z, a.w+b.w);
}

// ---------------------------------------------------------------- layernorm
__global__ __launch_bounds__(256)
void layernorm_kernel(const float* __restrict__ in, const float* __restrict__ g,
                      const float* __restrict__ b, float* __restrict__ out)
{
    int row = blockIdx.x;
    const float* xr = in + (size_t)row*DIM;
    int t = threadIdx.x;
    float2 v = *(const float2*)(xr + t*2);
    float s  = v.x + v.y;
    float s2 = v.x*v.x + v.y*v.y;
    #pragma unroll
    for (int o=32;o>=1;o>>=1){ s += __shfl_xor(s,o); s2 += __shfl_xor(s2,o); }
    __shared__ float ss[4], ss2[4];
    int w = t>>6;
    if ((t&63)==0){ ss[w]=s; ss2[w]=s2; }
    __syncthreads();
    s  = ss[0]+ss[1]+ss[2]+ss[3];
    s2 = ss2[0]+ss2[1]+ss2[2]+ss2[3];
    float mu  = s * (1.f/DIM);
    float var = s2 * (1.f/DIM) - mu*mu;
    float rstd = rsqrtf(var + 1e-5f);
    float2 gg = *(const float2*)(g + t*2);
    float2 bb = *(const float2*)(b + t*2);
    float2 o2;
    o2.x = (v.x-mu)*rstd*gg.x + bb.x;
    o2.y = (v.y-mu)*rstd*gg.y + bb.y;
    *(float2*)(out + (size_t)row*DIM + t*2) = o2;
}

// ---------------------------------------------------------------- generic GEMM
// C[M,N] = act(A[M,K] @ W[N,K]^T + bias) (+ C if RES). Row-major, lda/ldw/ldc in elems.
// ACT: 0 none, 1 softplus
template<int ACT, int BIAS, int RES>
__global__ __launch_bounds__(256)
void gemm_f32(const float* __restrict__ A, int lda,
              const float* __restrict__ W, int ldw,
              const float* __restrict__ bias,
              float* __restrict__ C, int ldc,
              int M, int N, int K)
{
    __shared__ float As[16][64];
    __shared__ float Ws[16][64];
    int t = threadIdx.x;
    int tx = t & 15, ty = t >> 4;
    int m0 = blockIdx.y * 64, n0 = blockIdx.x * 64;
    int loadRow = t >> 2;
    int loadK   = (t & 3) << 2;
    float acc[4][4] = {};
    for (int k0 = 0; k0 < K; k0 += 16) {
        {
            int gr = m0 + loadRow;
            float4 a4 = make_float4(0.f,0.f,0.f,0.f);
            if (gr < M) a4 = *(const float4*)(A + (size_t)gr*lda + k0 + loadK);
            As[loadK+0][loadRow] = a4.x;
            As[loadK+1][loadRow] = a4.y;
            As[loadK+2][loadRow] = a4.z;
            As[loadK+3][loadRow] = a4.w;
            int gn = n0 + loadRow;
            float4 w4 = make_float4(0.f,0.f,0.f,0.f);
            if (gn < N) w4 = *(const float4*)(W + (size_t)gn*ldw + k0 + loadK);
            Ws[loadK+0][loadRow] = w4.x;
            Ws[loadK+1][loadRow] = w4.y;
            Ws[loadK+2][loadRow] = w4.z;
            Ws[loadK+3][loadRow] = w4.w;
        }
        __syncthreads();
        #pragma unroll
        for (int k = 0; k < 16; ++k) {
            float4 a4 = *(const float4*)&As[k][ty<<2];
            float4 w4 = *(const float4*)&Ws[k][tx<<2];
            float a[4] = {a4.x,a4.y,a4.z,a4.w};
            float w[4] = {w4.x,w4.y,w4.z,w4.w};
            #pragma unroll
            for (int i=0;i<4;i++)
                #pragma unroll
                for (int j=0;j<4;j++)
                    acc[i][j] = fmaf(a[i], w[j], acc[i][j]);
        }
        __syncthreads();
    }
    #pragma unroll
    for (int i=0;i<4;i++){
        int row = m0 + (ty<<2) + i;
        if (row >= M) continue;
        #pragma unroll
        for (int j=0;j<4;j++){
            int col = n0 + (tx<<2) + j;
            if (col >= N) continue;
            float v = acc[i][j];
            if (BIAS) v += bias[col];
            if (ACT==1) v = (v > 20.f) ? v : log1pf(__expf(v));
            float* cp = C + (size_t)row*ldc + col;
            if (RES) v += *cp;
            *cp = v;
        }
    }
}

// ---------------------------------------------------------------- causal depthwise conv + SiLU
__global__ __launch_bounds__(256)
void conv_silu_kernel(const float* __restrict__ xz, const float* __restrict__ cw,
                      const float* __restrict__ cb, float* __restrict__ u)
{
    int idx = blockIdx.x*256 + threadIdx.x;   // 0 .. NTOK*DINNER-1
    int d = idx & (DINNER-1);
    int row = idx >> 10;
    int l = row & (SEQ-1);
    int bbase = row - l;                      // b*SEQ
    float acc = cb[d];
    #pragma unroll
    for (int k=0;k<DCONV;k++){
        int ls = l - (DCONV-1) + k;
        if (ls >= 0)
            acc = fmaf(xz[((size_t)(bbase+ls))*(2*DINNER) + d], cw[d*DCONV+k], acc);
    }
    u[idx] = acc * sigmoidf_(acc);
}

// ---------------------------------------------------------------- selective scan (fused D-skip + z-gate)
__global__ __launch_bounds__(256)
void scan_kernel(const float* __restrict__ delta, const float* __restrict__ u,
                 const float* __restrict__ xdbl, const float* __restrict__ xz,
                 const float* __restrict__ A_log, const float* __restrict__ D_skip,
                 float* __restrict__ y)
{
    int blk = blockIdx.x;        // 0..255
    int b = blk >> 6;
    int dbase = (blk & 63) << 4;
    int t = threadIdx.x;
    int s = t & 15;
    int d = dbase + (t >> 4);
    float Av = -__expf(A_log[d*DSTATE + s]);
    float Dv = D_skip[d];
    float hst = 0.f;
    size_t rowbase = (size_t)b * SEQ;
    for (int tt=0; tt<SEQ; ++tt){
        size_t row = rowbase + tt;
        float dlt = delta[row*DINNER + d];
        float uv  = u[row*DINNER + d];
        float Bv  = xdbl[row*64 + DTRANK + s];
        float Cv  = xdbl[row*64 + DTRANK + DSTATE + s];
        float dA = __expf(dlt * Av);
        hst = fmaf(dA, hst, dlt*uv*Bv);
        float p = hst * Cv;
        p += __shfl_xor(p, 8, 16);
        p += __shfl_xor(p, 4, 16);
        p += __shfl_xor(p, 2, 16);
        p += __shfl_xor(p, 1, 16);
        if (s == 0){
            float zv = xz[row*(2*DINNER) + DINNER + d];
            float yv = (p + uv*Dv) * (zv * sigmoidf_(zv));
            y[row*DINNER + d] = yv;
        }
    }
}

// ---------------------------------------------------------------- fused cross-attention (per token)
__global__ __launch_bounds__(256)
void attn_kernel(const float* __restrict__ q, const float* __restrict__ k,
                 const float* __restrict__ v, float* __restrict__ outp,
                 float* __restrict__ attn_mean)
{
    __shared__ float qs[DIM];
    __shared__ float sc[HEADS][CTX];
    int row = blockIdx.x;           // b*SEQ + l
    int b = row >> 10;
    int t = threadIdx.x;
    qs[t]       = q[(size_t)row*DIM + t];
    qs[t+256]   = q[(size_t)row*DIM + t + 256];
    __syncthreads();
    // scores
    for (int p = t; p < HEADS*CTX; p += 256){
        int h = p / CTX, si = p - h*CTX;
        const float* kp = k + ((size_t)(b*CTX + si))*DIM + h*DH;
        const float* qp = qs + h*DH;
        float acc = 0.f;
        #pragma unroll 8
        for (int i=0;i<DH;i++) acc = fmaf(qp[i], kp[i], acc);
        sc[h][si] = acc * 0.125f;   // 1/sqrt(64)
    }
    __syncthreads();
    // softmax: wave w handles heads 2w, 2w+1
    int wv = t >> 6, ln = t & 63;
    #pragma unroll
    for (int hh=0; hh<2; ++hh){
        int h = wv*2 + hh;
        float v1 = (ln < CTX) ? sc[h][ln] : -1e30f;
        float v2 = (ln+64 < CTX) ? sc[h][ln+64] : -1e30f;
        float m = fmaxf(v1,v2);
        #pragma unroll
        for (int o=32;o>=1;o>>=1) m = fmaxf(m, __shfl_xor(m,o));
        float e1 = (ln < CTX) ? __expf(v1-m) : 0.f;
        float e2 = (ln+64 < CTX) ? __expf(v2-m) : 0.f;
        float ssum = e1+e2;
        #pragma unroll
        for (int o=32;o>=1;o>>=1) ssum += __shfl_xor(ssum,o);
        float inv = 1.f/ssum;
        if (ln < CTX)    sc[h][ln]    = e1*inv;
        if (ln+64 < CTX) sc[h][ln+64] = e2*inv;
    }
    __syncthreads();
    // out = attn @ v
    for (int dim = t; dim < DIM; dim += 256){
        int h = dim >> 6;
        float acc = 0.f;
        for (int si=0; si<CTX; ++si)
            acc = fmaf(sc[h][si], v[((size_t)(b*CTX+si))*DIM + dim], acc);
        outp[(size_t)row*DIM + dim] = acc;
    }
    // head-averaged attention map -> final output
    if (t < CTX){
        float acc = 0.f;
        #pragma unroll
        for (int h=0;h<HEADS;h++) acc += sc[h][t];
        attn_mean[(size_t)row*CTX + t] = acc * (1.f/HEADS);
    }
}

// ---------------------------------------------------------------- launcher
extern "C" void kernel_launch(void* const* d_in, const int* in_sizes, int n_in,
                              void* d_out, int out_size, void* d_ws, size_t ws_size,
                              hipStream_t stream)
{
    (void)in_sizes; (void)n_in; (void)out_size; (void)ws_size;
    const int*   x        = (const int*)  d_in[0];
    const float* context  = (const float*)d_in[1];
    const float* tok_emb  = (const float*)d_in[2];
    const float* pos_emb  = (const float*)d_in[3];
    const float* ln1_g    = (const float*)d_in[4];
    const float* ln1_b    = (const float*)d_in[5];
    const float* in_w     = (const float*)d_in[6];
    const float* conv_w   = (const float*)d_in[7];
    const float* conv_b   = (const float*)d_in[8];
    const float* xproj_w  = (const float*)d_in[9];
    const float* dt_w     = (const float*)d_in[10];
    const float* dt_b     = (const float*)d_in[11];
    const float* A_log    = (const float*)d_in[12];
    const float* D_skip   = (const float*)d_in[13];
    const float* out_w    = (const float*)d_in[14];
    const float* ln2_g    = (const float*)d_in[15];
    const float* ln2_b    = (const float*)d_in[16];
    const float* ain_w    = (const float*)d_in[17];
    const float* ain_b    = (const float*)d_in[18];
    const float* aout_w   = (const float*)d_in[19];
    const float* aout_b   = (const float*)d_in[20];
    const float* lnf_g    = (const float*)d_in[21];
    const float* lnf_b    = (const float*)d_in[22];
    const float* logit_w  = (const float*)d_in[23];
    const float* logit_b  = (const float*)d_in[24];
    float* out = (float*)d_out;

    float* ws = (float*)d_ws;
    size_t off = 0;
    float* hbuf  = ws + off;  off += (size_t)NTOK*DIM;       // 2.10M
    float* tnorm = ws + off;  off += (size_t)NTOK*DIM;       // 2.10M
    float* xz    = ws + off;  off += (size_t)NTOK*2*DINNER;  // 8.39M
    float* ubuf  = ws + off;  off += (size_t)NTOK*DINNER;    // 4.19M
    float* xdbl  = ws + off;  off += (size_t)NTOK*64;        // 0.26M
    float* dbuf  = ws + off;  off += (size_t)NTOK*DINNER;    // 4.19M
    float* ybuf  = ws + off;  off += (size_t)NTOK*DINNER;    // 4.19M
    // reuse (dead after scan): q/attn-out alias ubuf, k/v alias dbuf
    float* qbuf  = ubuf;
    float* abuf  = ubuf + (size_t)NTOK*DIM;
    float* kbuf  = dbuf;
    float* vbuf  = dbuf + (size_t)BATCH*CTX*DIM;

    embed_kernel<<<NTOK, 128, 0, stream>>>(x, tok_emb, pos_emb, hbuf);

    float* attn_out_base = out + (size_t)NTOK*VOCAB;

    for (int i = 0; i < DEPTH; ++i){
        // ln1
        layernorm_kernel<<<NTOK, 256, 0, stream>>>(hbuf, ln1_g + i*DIM, ln1_b + i*DIM, tnorm);
        // in_proj: [4096,512]@[2048,512]^T -> xz
        gemm_f32<0,0,0><<<dim3((2*DINNER)/64, NTOK/64), 256, 0, stream>>>(
            tnorm, DIM, in_w + (size_t)i*2*DINNER*DIM, DIM, nullptr,
            xz, 2*DINNER, NTOK, 2*DINNER, DIM);
        // causal depthwise conv + SiLU -> ubuf
        conv_silu_kernel<<<(NTOK*DINNER)/256, 256, 0, stream>>>(
            xz, conv_w + (size_t)i*DINNER*DCONV, conv_b + i*DINNER, ubuf);
        // x_proj: [4096,1024]@[64,1024]^T -> xdbl
        gemm_f32<0,0,0><<<dim3(1, NTOK/64), 256, 0, stream>>>(
            ubuf, DINNER, xproj_w + (size_t)i*64*DINNER, DINNER, nullptr,
            xdbl, 64, NTOK, 64, DINNER);
        // dt_proj + softplus: [4096,32(stride64)]@[1024,32]^T -> dbuf
        gemm_f32<1,1,0><<<dim3(DINNER/64, NTOK/64), 256, 0, stream>>>(
            xdbl, 64, dt_w + (size_t)i*DINNER*DTRANK, DTRANK, dt_b + i*DINNER,
            dbuf, DINNER, NTOK, DINNER, DTRANK);
        // selective scan (+D skip, +z gate) -> ybuf
        scan_kernel<<<BATCH*(DINNER/16), 256, 0, stream>>>(
            dbuf, ubuf, xdbl, xz, A_log + (size_t)i*DINNER*DSTATE, D_skip + i*DINNER, ybuf);
        // out_proj + residual into hbuf
        gemm_f32<0,0,1><<<dim3(DIM/64, NTOK/64), 256, 0, stream>>>(
            ybuf, DINNER, out_w + (size_t)i*DIM*DINNER, DINNER, nullptr,
            hbuf, DIM, NTOK, DIM, DINNER);
        // ln2
        layernorm_kernel<<<NTOK, 256, 0, stream>>>(hbuf, ln2_g + i*DIM, ln2_b + i*DIM, tnorm);
        // q / k / v projections
        gemm_f32<0,1,0><<<dim3(DIM/64, NTOK/64), 256, 0, stream>>>(
            tnorm, DIM, ain_w + (size_t)i*3*DIM*DIM, DIM, ain_b + (size_t)i*3*DIM,
            qbuf, DIM, NTOK, DIM, DIM);
        gemm_f32<0,1,0><<<dim3(DIM/64, (BATCH*CTX+63)/64), 256, 0, stream>>>(
            context, DIM, ain_w + (size_t)i*3*DIM*DIM + (size_t)DIM*DIM, DIM,
            ain_b + (size_t)i*3*DIM + DIM, kbuf, DIM, BATCH*CTX, DIM, DIM);
        gemm_f32<0,1,0><<<dim3(DIM/64, (BATCH*CTX+63)/64), 256, 0, stream>>>(
            context, DIM, ain_w + (size_t)i*3*DIM*DIM + (size_t)2*DIM*DIM, DIM,
            ain_b + (size_t)i*3*DIM + 2*DIM, vbuf, DIM, BATCH*CTX, DIM, DIM);
        // fused attention (+ mean attn map straight into d_out)
        attn_kernel<<<NTOK, 256, 0, stream>>>(qbuf, kbuf, vbuf, abuf,
            attn_out_base + (size_t)i*NTOK*CTX);
        // attn out proj + residual into hbuf
        gemm_f32<0,1,1><<<dim3(DIM/64, NTOK/64), 256, 0, stream>>>(
            abuf, DIM, aout_w + (size_t)i*DIM*DIM, DIM, aout_b + i*DIM,
            hbuf, DIM, NTOK, DIM, DIM);
    }
    // final layernorm
    layernorm_kernel<<<NTOK, 256, 0, stream>>>(hbuf, lnf_g, lnf_b, tnorm);
    // logits: [4096,512]@[10000,512]^T + bias -> out
    gemm_f32<0,1,0><<<dim3((VOCAB+63)/64, NTOK/64), 256, 0, stream>>>(
        tnorm, DIM, logit_w, DIM, logit_b, out, VOCAB, NTOK, VOCAB, DIM);
}

// Round 2
// 2835.804 us; speedup vs baseline: 1.7268x; 1.7268x over previous
//
#include <hip/hip_runtime.h>
#include <hip/hip_bf16.h>
#include <math.h>

#define DIM 512
#define VOCAB 10000
#define DEPTH 3
#define DSTATE 16
#define DCONV 4
#define DINNER 1024
#define DTRANK 32
#define BATCH 4
#define SEQ 1024
#define CTX 98
#define HEADS 8
#define DH 64
#define NTOK (BATCH*SEQ)   // 4096
#define NC 32              // scan chunks
#define LC 32              // chunk length

__device__ __forceinline__ float sigmoidf_(float x){ return 1.f/(1.f+__expf(-x)); }

// ---------------------------------------------------------------- embedding
__global__ __launch_bounds__(128)
void embed_kernel(const int* __restrict__ x,
                  const float* __restrict__ tok_emb,
                  const float* __restrict__ pos_emb,
                  float* __restrict__ h)
{
    int row = blockIdx.x;            // 0..4095 = b*SEQ + l
    int l = row & (SEQ-1);
    int tok = x[row];
    const float4* te = (const float4*)(tok_emb + (size_t)tok*DIM);
    const float4* pe = (const float4*)(pos_emb + (size_t)l*DIM);
    float4* hp = (float4*)(h + (size_t)row*DIM);
    int i = threadIdx.x;             // DIM/4 = 128
    float4 a = te[i], b = pe[i];
    hp[i] = make_float4(a.x+b.x, a.y+b.y, a.z+b.z, a.w+b.w);
}

// ---------------------------------------------------------------- layernorm
__global__ __launch_bounds__(256)
void layernorm_kernel(const float* __restrict__ in, const float* __restrict__ g,
                      const float* __restrict__ b, float* __restrict__ out)
{
    int row = blockIdx.x;
    const float* xr = in + (size_t)row*DIM;
    int t = threadIdx.x;
    float2 v = *(const float2*)(xr + t*2);
    float s  = v.x + v.y;
    float s2 = v.x*v.x + v.y*v.y;
    #pragma unroll
    for (int o=32;o>=1;o>>=1){ s += __shfl_xor(s,o); s2 += __shfl_xor(s2,o); }
    __shared__ float ss[4], ss2[4];
    int w = t>>6;
    if ((t&63)==0){ ss[w]=s; ss2[w]=s2; }
    __syncthreads();
    s  = ss[0]+ss[1]+ss[2]+ss[3];
    s2 = ss2[0]+ss2[1]+ss2[2]+ss2[3];
    float mu  = s * (1.f/DIM);
    float var = s2 * (1.f/DIM) - mu*mu;
    float rstd = rsqrtf(var + 1e-5f);
    float2 gg = *(const float2*)(g + t*2);
    float2 bb = *(const float2*)(b + t*2);
    float2 o2;
    o2.x = (v.x-mu)*rstd*gg.x + bb.x;
    o2.y = (v.y-mu)*rstd*gg.y + bb.y;
    *(float2*)(out + (size_t)row*DIM + t*2) = o2;
}

// ---------------------------------------------------------------- generic GEMM
// C[M,N] = act(A[M,K] @ W[N,K]^T + bias) (+ C if RES). Row-major, lda/ldw/ldc in elems.
// ACT: 0 none, 1 softplus
template<int ACT, int BIAS, int RES>
__global__ __launch_bounds__(256)
void gemm_f32(const float* __restrict__ A, int lda,
              const float* __restrict__ W, int ldw,
              const float* __restrict__ bias,
              float* __restrict__ C, int ldc,
              int M, int N, int K)
{
    __shared__ float As[16][64];
    __shared__ float Ws[16][64];
    int t = threadIdx.x;
    int tx = t & 15, ty = t >> 4;
    int m0 = blockIdx.y * 64, n0 = blockIdx.x * 64;
    int loadRow = t >> 2;
    int loadK   = (t & 3) << 2;
    float acc[4][4] = {};
    for (int k0 = 0; k0 < K; k0 += 16) {
        {
            int gr = m0 + loadRow;
            float4 a4 = make_float4(0.f,0.f,0.f,0.f);
            if (gr < M) a4 = *(const float4*)(A + (size_t)gr*lda + k0 + loadK);
            As[loadK+0][loadRow] = a4.x;
            As[loadK+1][loadRow] = a4.y;
            As[loadK+2][loadRow] = a4.z;
            As[loadK+3][loadRow] = a4.w;
            int gn = n0 + loadRow;
            float4 w4 = make_float4(0.f,0.f,0.f,0.f);
            if (gn < N) w4 = *(const float4*)(W + (size_t)gn*ldw + k0 + loadK);
            Ws[loadK+0][loadRow] = w4.x;
            Ws[loadK+1][loadRow] = w4.y;
            Ws[loadK+2][loadRow] = w4.z;
            Ws[loadK+3][loadRow] = w4.w;
        }
        __syncthreads();
        #pragma unroll
        for (int k = 0; k < 16; ++k) {
            float4 a4 = *(const float4*)&As[k][ty<<2];
            float4 w4 = *(const float4*)&Ws[k][tx<<2];
            float a[4] = {a4.x,a4.y,a4.z,a4.w};
            float w[4] = {w4.x,w4.y,w4.z,w4.w};
            #pragma unroll
            for (int i=0;i<4;i++)
                #pragma unroll
                for (int j=0;j<4;j++)
                    acc[i][j] = fmaf(a[i], w[j], acc[i][j]);
        }
        __syncthreads();
    }
    #pragma unroll
    for (int i=0;i<4;i++){
        int row = m0 + (ty<<2) + i;
        if (row >= M) continue;
        #pragma unroll
        for (int j=0;j<4;j++){
            int col = n0 + (tx<<2) + j;
            if (col >= N) continue;
            float v = acc[i][j];
            if (BIAS) v += bias[col];
            if (ACT==1) v = (v > 20.f) ? v : log1pf(__expf(v));
            float* cp = C + (size_t)row*ldc + col;
            if (RES) v += *cp;
            *cp = v;
        }
    }
}

// ---------------------------------------------------------------- causal depthwise conv + SiLU
__global__ __launch_bounds__(256)
void conv_silu_kernel(const float* __restrict__ xz, const float* __restrict__ cw,
                      const float* __restrict__ cb, float* __restrict__ u)
{
    int idx = blockIdx.x*256 + threadIdx.x;   // 0 .. NTOK*DINNER-1
    int d = idx & (DINNER-1);
    int row = idx >> 10;
    int l = row & (SEQ-1);
    int bbase = row - l;                      // b*SEQ
    float acc = cb[d];
    #pragma unroll
    for (int k=0;k<DCONV;k++){
        int ls = l - (DCONV-1) + k;
        if (ls >= 0)
            acc = fmaf(xz[((size_t)(bbase+ls))*(2*DINNER) + d], cw[d*DCONV+k], acc);
    }
    u[idx] = acc * sigmoidf_(acc);
}

// ---------------------------------------------------------------- chunked selective scan
// Linear recurrence h[t] = exp(delta_t*A)*h[t-1] + delta_t*u_t*B_t, split into
// NC chunks of LC. Chunk decay product = exp(A * sum(delta)) -> only track
// sum(delta). Pass1: local scans (h0=0) -> hend + dsum. Pass2: carry scan over
// chunks -> hin. Pass3: local scan seeded with hin, fused C-reduce + D-skip +
// z-gate -> y.

// pass1: one thread per (b, d, chunk); 16 states in registers
__global__ __launch_bounds__(256)
void scan_pass1(const float* __restrict__ delta, const float* __restrict__ u,
                const float* __restrict__ xdbl, const float* __restrict__ A_log,
                float* __restrict__ hend, float* __restrict__ dsum_out)
{
    __shared__ float bc[LC][32];             // B (j<16) and C (j>=16) for chunk rows
    int c = blockIdx.x;
    int b = blockIdx.y >> 2, dg = blockIdx.y & 3;
    int t = threadIdx.x;
    int d = dg*256 + t;
    int rowbase = b*SEQ + c*LC;
    for (int idx = t; idx < LC*32; idx += 256){
        int r = idx >> 5, j = idx & 31;
        bc[r][j] = xdbl[(size_t)(rowbase + r)*64 + DTRANK + j];
    }
    float Av[DSTATE];
    #pragma unroll
    for (int s4 = 0; s4 < 4; ++s4){
        float4 a4 = *(const float4*)(A_log + (size_t)d*DSTATE + s4*4);
        Av[s4*4+0] = -__expf(a4.x);
        Av[s4*4+1] = -__expf(a4.y);
        Av[s4*4+2] = -__expf(a4.z);
        Av[s4*4+3] = -__expf(a4.w);
    }
    __syncthreads();
    float h[DSTATE] = {};
    float ds = 0.f;
    for (int tt = 0; tt < LC; ++tt){
        size_t row = (size_t)(rowbase + tt);
        float dlt = delta[row*DINNER + d];
        float uv  = u[row*DINNER + d];
        ds += dlt;
        float du = dlt*uv;
        #pragma unroll
        for (int s = 0; s < DSTATE; ++s)
            h[s] = fmaf(__expf(dlt*Av[s]), h[s], du*bc[tt][s]);
    }
    size_t base = ((size_t)(b*NC + c)*DINNER + d)*DSTATE;
    #pragma unroll
    for (int s4=0;s4<4;s4++)
        *(float4*)(hend + base + s4*4) =
            make_float4(h[s4*4],h[s4*4+1],h[s4*4+2],h[s4*4+3]);
    dsum_out[(size_t)(b*NC+c)*DINNER + d] = ds;
}

// pass2: carry scan across chunks; one thread per (b,d,s)
__global__ __launch_bounds__(256)
void scan_pass2(const float* __restrict__ hend, const float* __restrict__ dsum,
                const float* __restrict__ A_log, float* __restrict__ hin)
{
    int gid = blockIdx.x*256 + threadIdx.x;   // (b*DINNER+d)*16 + s
    int s = gid & 15;
    int bd = gid >> 4;
    int d = bd & (DINNER-1);
    int b = bd >> 10;
    float Av = -__expf(A_log[(size_t)d*DSTATE + s]);
    float h = 0.f;
    for (int c = 0; c < NC; ++c){
        size_t idx = ((size_t)(b*NC + c)*DINNER + d)*DSTATE + s;
        hin[idx] = h;
        h = fmaf(__expf(Av*dsum[(size_t)(b*NC+c)*DINNER + d]), h, hend[idx]);
    }
}

// pass3: seeded local scan + y = sum_s h*C, + u*D, * silu(z)
__global__ __launch_bounds__(256)
void scan_pass3(const float* __restrict__ delta, const float* __restrict__ u,
                const float* __restrict__ xdbl, const float* __restrict__ xz,
                const float* __restrict__ A_log, const float* __restrict__ D_skip,
                const float* __restrict__ hin, float* __restrict__ y)
{
    __shared__ float bc[LC][32];
    int c = blockIdx.x;
    int b = blockIdx.y >> 2, dg = blockIdx.y & 3;
    int t = threadIdx.x;
    int d = dg*256 + t;
    int rowbase = b*SEQ + c*LC;
    for (int idx = t; idx < LC*32; idx += 256){
        int r = idx >> 5, j = idx & 31;
        bc[r][j] = xdbl[(size_t)(rowbase + r)*64 + DTRANK + j];
    }
    float Av[DSTATE];
    #pragma unroll
    for (int s4 = 0; s4 < 4; ++s4){
        float4 a4 = *(const float4*)(A_log + (size_t)d*DSTATE + s4*4);
        Av[s4*4+0] = -__expf(a4.x);
        Av[s4*4+1] = -__expf(a4.y);
        Av[s4*4+2] = -__expf(a4.z);
        Av[s4*4+3] = -__expf(a4.w);
    }
    float h[DSTATE];
    size_t hbase = ((size_t)(b*NC + c)*DINNER + d)*DSTATE;
    #pragma unroll
    for (int s4=0;s4<4;s4++){
        float4 h4 = *(const float4*)(hin + hbase + s4*4);
        h[s4*4+0]=h4.x; h[s4*4+1]=h4.y; h[s4*4+2]=h4.z; h[s4*4+3]=h4.w;
    }
    float Dv = D_skip[d];
    __syncthreads();
    for (int tt = 0; tt < LC; ++tt){
        size_t row = (size_t)(rowbase + tt);
        float dlt = delta[row*DINNER + d];
        float uv  = u[row*DINNER + d];
        float du = dlt*uv;
        float yv = 0.f;
        #pragma unroll
        for (int s = 0; s < DSTATE; ++s){
            h[s] = fmaf(__expf(dlt*Av[s]), h[s], du*bc[tt][s]);
            yv = fmaf(h[s], bc[tt][16+s], yv);
        }
        float zv = xz[row*(2*DINNER) + DINNER + d];
        y[row*DINNER + d] = (yv + uv*Dv) * (zv * sigmoidf_(zv));
    }
}

// ---------------------------------------------------------------- fused cross-attention (per token)
__global__ __launch_bounds__(256)
void attn_kernel(const float* __restrict__ q, const float* __restrict__ k,
                 const float* __restrict__ v, float* __restrict__ outp,
                 float* __restrict__ attn_mean)
{
    __shared__ float qs[DIM];
    __shared__ float sc[HEADS][CTX];
    int row = blockIdx.x;           // b*SEQ + l
    int b = row >> 10;
    int t = threadIdx.x;
    qs[t]       = q[(size_t)row*DIM + t];
    qs[t+256]   = q[(size_t)row*DIM + t + 256];
    __syncthreads();
    // scores
    for (int p = t; p < HEADS*CTX; p += 256){
        int h = p / CTX, si = p - h*CTX;
        const float* kp = k + ((size_t)(b*CTX + si))*DIM + h*DH;
        const float* qp = qs + h*DH;
        float acc = 0.f;
        #pragma unroll 8
        for (int i=0;i<DH;i++) acc = fmaf(qp[i], kp[i], acc);
        sc[h][si] = acc * 0.125f;   // 1/sqrt(64)
    }
    __syncthreads();
    // softmax: wave w handles heads 2w, 2w+1
    int wv = t >> 6, ln = t & 63;
    #pragma unroll
    for (int hh=0; hh<2; ++hh){
        int h = wv*2 + hh;
        float v1 = (ln < CTX) ? sc[h][ln] : -1e30f;
        float v2 = (ln+64 < CTX) ? sc[h][ln+64] : -1e30f;
        float m = fmaxf(v1,v2);
        #pragma unroll
        for (int o=32;o>=1;o>>=1) m = fmaxf(m, __shfl_xor(m,o));
        float e1 = (ln < CTX) ? __expf(v1-m) : 0.f;
        float e2 = (ln+64 < CTX) ? __expf(v2-m) : 0.f;
        float ssum = e1+e2;
        #pragma unroll
        for (int o=32;o>=1;o>>=1) ssum += __shfl_xor(ssum,o);
        float inv = 1.f/ssum;
        if (ln < CTX)    sc[h][ln]    = e1*inv;
        if (ln+64 < CTX) sc[h][ln+64] = e2*inv;
    }
    __syncthreads();
    // out = attn @ v
    for (int dim = t; dim < DIM; dim += 256){
        int h = dim >> 6;
        float acc = 0.f;
        for (int si=0; si<CTX; ++si)
            acc = fmaf(sc[h][si], v[((size_t)(b*CTX+si))*DIM + dim], acc);
        outp[(size_t)row*DIM + dim] = acc;
    }
    // head-averaged attention map -> final output
    if (t < CTX){
        float acc = 0.f;
        #pragma unroll
        for (int h=0;h<HEADS;h++) acc += sc[h][t];
        attn_mean[(size_t)row*CTX + t] = acc * (1.f/HEADS);
    }
}

// ---------------------------------------------------------------- launcher
extern "C" void kernel_launch(void* const* d_in, const int* in_sizes, int n_in,
                              void* d_out, int out_size, void* d_ws, size_t ws_size,
                              hipStream_t stream)
{
    (void)in_sizes; (void)n_in; (void)out_size; (void)ws_size;
    const int*   x        = (const int*)  d_in[0];
    const float* context  = (const float*)d_in[1];
    const float* tok_emb  = (const float*)d_in[2];
    const float* pos_emb  = (const float*)d_in[3];
    const float* ln1_g    = (const float*)d_in[4];
    const float* ln1_b    = (const float*)d_in[5];
    const float* in_w     = (const float*)d_in[6];
    const float* conv_w   = (const float*)d_in[7];
    const float* conv_b   = (const float*)d_in[8];
    const float* xproj_w  = (const float*)d_in[9];
    const float* dt_w     = (const float*)d_in[10];
    const float* dt_b     = (const float*)d_in[11];
    const float* A_log    = (const float*)d_in[12];
    const float* D_skip   = (const float*)d_in[13];
    const float* out_w    = (const float*)d_in[14];
    const float* ln2_g    = (const float*)d_in[15];
    const float* ln2_b    = (const float*)d_in[16];
    const float* ain_w    = (const float*)d_in[17];
    const float* ain_b    = (const float*)d_in[18];
    const float* aout_w   = (const float*)d_in[19];
    const float* aout_b   = (const float*)d_in[20];
    const float* lnf_g    = (const float*)d_in[21];
    const float* lnf_b    = (const float*)d_in[22];
    const float* logit_w  = (const float*)d_in[23];
    const float* logit_b  = (const float*)d_in[24];
    float* out = (float*)d_out;

    float* ws = (float*)d_ws;
    size_t off = 0;
    float* hbuf  = ws + off;  off += (size_t)NTOK*DIM;       // 2.10M
    float* tnorm = ws + off;  off += (size_t)NTOK*DIM;       // 2.10M
    float* xz    = ws + off;  off += (size_t)NTOK*2*DINNER;  // 8.39M
    float* ubuf  = ws + off;  off += (size_t)NTOK*DINNER;    // 4.19M
    float* xdbl  = ws + off;  off += (size_t)NTOK*64;        // 0.26M
    float* dbuf  = ws + off;  off += (size_t)NTOK*DINNER;    // 4.19M
    float* ybuf  = ws + off;  off += (size_t)NTOK*DINNER;    // 4.19M
    // reuse (dead after scan): q/attn-out alias ubuf, k/v alias dbuf
    float* qbuf  = ubuf;
    float* abuf  = ubuf + (size_t)NTOK*DIM;
    float* kbuf  = dbuf;
    float* vbuf  = dbuf + (size_t)BATCH*CTX*DIM;
    // scan scratch lives in the (dead until the end) logits region of d_out:
    // needs 2M + 2M + 0.125M floats << NTOK*VOCAB = 40.96M floats
    float* hend  = out;                                      // [B][NC][DINNER][16]
    float* hinb  = out + (size_t)BATCH*NC*DINNER*DSTATE;     // same shape
    float* dsumb = hinb + (size_t)BATCH*NC*DINNER*DSTATE;    // [B][NC][DINNER]

    embed_kernel<<<NTOK, 128, 0, stream>>>(x, tok_emb, pos_emb, hbuf);

    float* attn_out_base = out + (size_t)NTOK*VOCAB;

    for (int i = 0; i < DEPTH; ++i){
        const float* Ai = A_log + (size_t)i*DINNER*DSTATE;
        // ln1
        layernorm_kernel<<<NTOK, 256, 0, stream>>>(hbuf, ln1_g + i*DIM, ln1_b + i*DIM, tnorm);
        // in_proj: [4096,512]@[2048,512]^T -> xz
        gemm_f32<0,0,0><<<dim3((2*DINNER)/64, NTOK/64), 256, 0, stream>>>(
            tnorm, DIM, in_w + (size_t)i*2*DINNER*DIM, DIM, nullptr,
            xz, 2*DINNER, NTOK, 2*DINNER, DIM);
        // causal depthwise conv + SiLU -> ubuf
        conv_silu_kernel<<<(NTOK*DINNER)/256, 256, 0, stream>>>(
            xz, conv_w + (size_t)i*DINNER*DCONV, conv_b + i*DINNER, ubuf);
        // x_proj: [4096,1024]@[64,1024]^T -> xdbl
        gemm_f32<0,0,0><<<dim3(1, NTOK/64), 256, 0, stream>>>(
            ubuf, DINNER, xproj_w + (size_t)i*64*DINNER, DINNER, nullptr,
            xdbl, 64, NTOK, 64, DINNER);
        // dt_proj + softplus: [4096,32(stride64)]@[1024,32]^T -> dbuf
        gemm_f32<1,1,0><<<dim3(DINNER/64, NTOK/64), 256, 0, stream>>>(
            xdbl, 64, dt_w + (size_t)i*DINNER*DTRANK, DTRANK, dt_b + i*DINNER,
            dbuf, DINNER, NTOK, DINNER, DTRANK);
        // chunked selective scan (+D skip, +z gate) -> ybuf
        scan_pass1<<<dim3(NC, BATCH*4), 256, 0, stream>>>(
            dbuf, ubuf, xdbl, Ai, hend, dsumb);
        scan_pass2<<<(BATCH*DINNER*DSTATE)/256, 256, 0, stream>>>(
            hend, dsumb, Ai, hinb);
        scan_pass3<<<dim3(NC, BATCH*4), 256, 0, stream>>>(
            dbuf, ubuf, xdbl, xz, Ai, D_skip + i*DINNER, hinb, ybuf);
        // out_proj + residual into hbuf
        gemm_f32<0,0,1><<<dim3(DIM/64, NTOK/64), 256, 0, stream>>>(
            ybuf, DINNER, out_w + (size_t)i*DIM*DINNER, DINNER, nullptr,
            hbuf, DIM, NTOK, DIM, DINNER);
        // ln2
        layernorm_kernel<<<NTOK, 256, 0, stream>>>(hbuf, ln2_g + i*DIM, ln2_b + i*DIM, tnorm);
        // q / k / v projections
        gemm_f32<0,1,0><<<dim3(DIM/64, NTOK/64), 256, 0, stream>>>(
            tnorm, DIM, ain_w + (size_t)i*3*DIM*DIM, DIM, ain_b + (size_t)i*3*DIM,
            qbuf, DIM, NTOK, DIM, DIM);
        gemm_f32<0,1,0><<<dim3(DIM/64, (BATCH*CTX+63)/64), 256, 0, stream>>>(
            context, DIM, ain_w + (size_t)i*3*DIM*DIM + (size_t)DIM*DIM, DIM,
            ain_b + (size_t)i*3*DIM + DIM, kbuf, DIM, BATCH*CTX, DIM, DIM);
        gemm_f32<0,1,0><<<dim3(DIM/64, (BATCH*CTX+63)/64), 256, 0, stream>>>(
            context, DIM, ain_w + (size_t)i*3*DIM*DIM + (size_t)2*DIM*DIM, DIM,
            ain_b + (size_t)i*3*DIM + 2*DIM, vbuf, DIM, BATCH*CTX, DIM, DIM);
        // fused attention (+ mean attn map straight into d_out)
        attn_kernel<<<NTOK, 256, 0, stream>>>(qbuf, kbuf, vbuf, abuf,
            attn_out_base + (size_t)i*NTOK*CTX);
        // attn out proj + residual into hbuf
        gemm_f32<0,1,1><<<dim3(DIM/64, NTOK/64), 256, 0, stream>>>(
            abuf, DIM, aout_w + (size_t)i*DIM*DIM, DIM, aout_b + i*DIM,
            hbuf, DIM, NTOK, DIM, DIM);
    }
    // final layernorm
    layernorm_kernel<<<NTOK, 256, 0, stream>>>(hbuf, lnf_g, lnf_b, tnorm);
    // logits: [4096,512]@[10000,512]^T + bias -> out
    gemm_f32<0,1,0><<<dim3((VOCAB+63)/64, NTOK/64), 256, 0, stream>>>(
        tnorm, DIM, logit_w, DIM, logit_b, out, VOCAB, NTOK, VOCAB, DIM);
}

// Round 3
// 1746.921 us; speedup vs baseline: 2.8032x; 1.6233x over previous
//
#include <hip/hip_runtime.h>
#include <hip/hip_bf16.h>
#include <math.h>

#define DIM 512
#define VOCAB 10000
#define NPAD 10240
#define DEPTH 3
#define DSTATE 16
#define DCONV 4
#define DINNER 1024
#define DTRANK 32
#define BATCH 4
#define SEQ 1024
#define CTX 98
#define HEADS 8
#define DH 64
#define NTOK (BATCH*SEQ)   // 4096
#define NC 32              // scan chunks
#define LC 32              // chunk length

typedef __attribute__((ext_vector_type(8))) short short8;
typedef __attribute__((ext_vector_type(4))) float f32x4;

__device__ __forceinline__ float sigmoidf_(float x){ return 1.f/(1.f+__expf(-x)); }

__device__ __forceinline__ void gload_lds16(const void* g, void* s){
    __builtin_amdgcn_global_load_lds(
        (const __attribute__((address_space(1))) void*)g,
        (__attribute__((address_space(3))) void*)s, 16, 0, 0);
}

// ---------------------------------------------------------------- fp32 -> bf16 convert
__global__ __launch_bounds__(256)
void f2bf_kernel(const float* __restrict__ in, __hip_bfloat16* __restrict__ out)
{
    int i = (blockIdx.x*256 + threadIdx.x)*8;
    float4 a = *(const float4*)(in+i);
    float4 b = *(const float4*)(in+i+4);
    union { __hip_bfloat16 v[8]; short8 s; } o;
    o.v[0]=__float2bfloat16(a.x); o.v[1]=__float2bfloat16(a.y);
    o.v[2]=__float2bfloat16(a.z); o.v[3]=__float2bfloat16(a.w);
    o.v[4]=__float2bfloat16(b.x); o.v[5]=__float2bfloat16(b.y);
    o.v[6]=__float2bfloat16(b.z); o.v[7]=__float2bfloat16(b.w);
    *(short8*)(out+i) = o.s;
}

// ---------------------------------------------------------------- embedding
__global__ __launch_bounds__(128)
void embed_kernel(const int* __restrict__ x,
                  const float* __restrict__ tok_emb,
                  const float* __restrict__ pos_emb,
                  float* __restrict__ h)
{
    int row = blockIdx.x;
    int l = row & (SEQ-1);
    int tok = x[row];
    const float4* te = (const float4*)(tok_emb + (size_t)tok*DIM);
    const float4* pe = (const float4*)(pos_emb + (size_t)l*DIM);
    float4* hp = (float4*)(h + (size_t)row*DIM);
    int i = threadIdx.x;
    float4 a = te[i], b = pe[i];
    hp[i] = make_float4(a.x+b.x, a.y+b.y, a.z+b.z, a.w+b.w);
}

// ---------------------------------------------------------------- layernorm (bf16 out)
__global__ __launch_bounds__(256)
void layernorm_kernel(const float* __restrict__ in, const float* __restrict__ g,
                      const float* __restrict__ b, __hip_bfloat16* __restrict__ out)
{
    int row = blockIdx.x;
    const float* xr = in + (size_t)row*DIM;
    int t = threadIdx.x;
    float2 v = *(const float2*)(xr + t*2);
    float s  = v.x + v.y;
    float s2 = v.x*v.x + v.y*v.y;
    #pragma unroll
    for (int o=32;o>=1;o>>=1){ s += __shfl_xor(s,o); s2 += __shfl_xor(s2,o); }
    __shared__ float ss[4], ss2[4];
    int w = t>>6;
    if ((t&63)==0){ ss[w]=s; ss2[w]=s2; }
    __syncthreads();
    s  = ss[0]+ss[1]+ss[2]+ss[3];
    s2 = ss2[0]+ss2[1]+ss2[2]+ss2[3];
    float mu  = s * (1.f/DIM);
    float var = s2 * (1.f/DIM) - mu*mu;
    float rstd = rsqrtf(var + 1e-5f);
    float2 gg = *(const float2*)(g + t*2);
    float2 bb = *(const float2*)(b + t*2);
    __hip_bfloat162 o2;
    o2.x = __float2bfloat16((v.x-mu)*rstd*gg.x + bb.x);
    o2.y = __float2bfloat16((v.y-mu)*rstd*gg.y + bb.y);
    *(__hip_bfloat162*)(out + (size_t)row*DIM + t*2) = o2;
}

// ---------------------------------------------------------------- bf16 MFMA GEMM
// C[M,N] = A[M,K](bf16) @ W[N,K](bf16)^T (+bias) (+C). 128x128 tile, BK=32,
// 256 thr = 4 waves, each wave 64x64 via 4x4 grid of 16x16x32 MFMAs.
template<int BIAS, int RES, int NCHECK>
__global__ __launch_bounds__(256)
void gemm_bf16(const __hip_bfloat16* __restrict__ A, int lda,
               const __hip_bfloat16* __restrict__ W, int ldw,
               const float* __restrict__ bias,
               float* __restrict__ C, int ldc, int Nstore, int K)
{
    __shared__ __hip_bfloat16 As[128*32];
    __shared__ __hip_bfloat16 Ws[128*32];
    int t = threadIdx.x;
    int w = t >> 6, l = t & 63;
    int m0 = blockIdx.y*128, n0 = blockIdx.x*128;
    int wm = (w>>1)*64, wn = (w&1)*64;
    int lrow = l & 15, lq = l >> 4;
    f32x4 acc[4][4];
    #pragma unroll
    for (int i=0;i<4;i++)
        #pragma unroll
        for (int j=0;j<4;j++)
            acc[i][j] = (f32x4){0.f,0.f,0.f,0.f};

    for (int k0 = 0; k0 < K; k0 += 32){
        __syncthreads();
        #pragma unroll
        for (int it = 0; it < 2; ++it){
            int p = it*256 + t;            // 16B chunk index, 512 chunks/tile
            int r = p >> 2, c = (p & 3)*8;
            gload_lds16(A + (size_t)(m0+r)*lda + k0 + c, As + p*8);
            gload_lds16(W + (size_t)(n0+r)*ldw + k0 + c, Ws + p*8);
        }
        __syncthreads();
        short8 a[4], b[4];
        #pragma unroll
        for (int mt=0;mt<4;mt++)
            a[mt] = *(const short8*)(As + (wm + mt*16 + lrow)*32 + lq*8);
        #pragma unroll
        for (int nt=0;nt<4;nt++)
            b[nt] = *(const short8*)(Ws + (wn + nt*16 + lrow)*32 + lq*8);
        #pragma unroll
        for (int mt=0;mt<4;mt++)
            #pragma unroll
            for (int nt=0;nt<4;nt++)
                acc[mt][nt] = __builtin_amdgcn_mfma_f32_16x16x32_bf16(
                    a[mt], b[nt], acc[mt][nt], 0, 0, 0);
    }
    // epilogue: D row = wm+mt*16+lq*4+r, col = wn+nt*16+lrow
    #pragma unroll
    for (int nt=0;nt<4;nt++){
        int col = n0 + wn + nt*16 + lrow;
        if (NCHECK && col >= Nstore) continue;
        float bv = BIAS ? bias[col] : 0.f;
        #pragma unroll
        for (int mt=0;mt<4;mt++){
            #pragma unroll
            for (int r=0;r<4;r++){
                int row = m0 + wm + mt*16 + lq*4 + r;
                float v = acc[mt][nt][r] + bv;
                float* cp = C + (size_t)row*ldc + col;
                if (RES) v += *cp;
                *cp = v;
            }
        }
    }
}

// ---------------------------------------------------------------- generic fp32 GEMM (small/odd shapes)
template<int ACT, int BIAS, int RES>
__global__ __launch_bounds__(256)
void gemm_f32(const float* __restrict__ A, int lda,
              const float* __restrict__ W, int ldw,
              const float* __restrict__ bias,
              float* __restrict__ C, int ldc,
              int M, int N, int K)
{
    __shared__ float As[16][64];
    __shared__ float Ws[16][64];
    int t = threadIdx.x;
    int tx = t & 15, ty = t >> 4;
    int m0 = blockIdx.y * 64, n0 = blockIdx.x * 64;
    int loadRow = t >> 2;
    int loadK   = (t & 3) << 2;
    float acc[4][4] = {};
    for (int k0 = 0; k0 < K; k0 += 16) {
        {
            int gr = m0 + loadRow;
            float4 a4 = make_float4(0.f,0.f,0.f,0.f);
            if (gr < M) a4 = *(const float4*)(A + (size_t)gr*lda + k0 + loadK);
            As[loadK+0][loadRow] = a4.x;
            As[loadK+1][loadRow] = a4.y;
            As[loadK+2][loadRow] = a4.z;
            As[loadK+3][loadRow] = a4.w;
            int gn = n0 + loadRow;
            float4 w4 = make_float4(0.f,0.f,0.f,0.f);
            if (gn < N) w4 = *(const float4*)(W + (size_t)gn*ldw + k0 + loadK);
            Ws[loadK+0][loadRow] = w4.x;
            Ws[loadK+1][loadRow] = w4.y;
            Ws[loadK+2][loadRow] = w4.z;
            Ws[loadK+3][loadRow] = w4.w;
        }
        __syncthreads();
        #pragma unroll
        for (int k = 0; k < 16; ++k) {
            float4 a4 = *(const float4*)&As[k][ty<<2];
            float4 w4 = *(const float4*)&Ws[k][tx<<2];
            float a[4] = {a4.x,a4.y,a4.z,a4.w};
            float w[4] = {w4.x,w4.y,w4.z,w4.w};
            #pragma unroll
            for (int i=0;i<4;i++)
                #pragma unroll
                for (int j=0;j<4;j++)
                    acc[i][j] = fmaf(a[i], w[j], acc[i][j]);
        }
        __syncthreads();
    }
    #pragma unroll
    for (int i=0;i<4;i++){
        int row = m0 + (ty<<2) + i;
        if (row >= M) continue;
        #pragma unroll
        for (int j=0;j<4;j++){
            int col = n0 + (tx<<2) + j;
            if (col >= N) continue;
            float v = acc[i][j];
            if (BIAS) v += bias[col];
            if (ACT==1) v = (v > 20.f) ? v : log1pf(__expf(v));
            float* cp = C + (size_t)row*ldc + col;
            if (RES) v += *cp;
            *cp = v;
        }
    }
}

// ---------------------------------------------------------------- causal depthwise conv + SiLU
__global__ __launch_bounds__(256)
void conv_silu_kernel(const float* __restrict__ xz, const float* __restrict__ cw,
                      const float* __restrict__ cb, float* __restrict__ u)
{
    int idx = blockIdx.x*256 + threadIdx.x;
    int d = idx & (DINNER-1);
    int row = idx >> 10;
    int l = row & (SEQ-1);
    int bbase = row - l;
    float acc = cb[d];
    #pragma unroll
    for (int k=0;k<DCONV;k++){
        int ls = l - (DCONV-1) + k;
        if (ls >= 0)
            acc = fmaf(xz[((size_t)(bbase+ls))*(2*DINNER) + d], cw[d*DCONV+k], acc);
    }
    u[idx] = acc * sigmoidf_(acc);
}

// ---------------------------------------------------------------- chunked selective scan
__global__ __launch_bounds__(256)
void scan_pass1(const float* __restrict__ delta, const float* __restrict__ u,
                const float* __restrict__ xdbl, const float* __restrict__ A_log,
                float* __restrict__ hend, float* __restrict__ dsum_out)
{
    __shared__ float bc[LC][32];
    int c = blockIdx.x;
    int b = blockIdx.y >> 2, dg = blockIdx.y & 3;
    int t = threadIdx.x;
    int d = dg*256 + t;
    int rowbase = b*SEQ + c*LC;
    for (int idx = t; idx < LC*32; idx += 256){
        int r = idx >> 5, j = idx & 31;
        bc[r][j] = xdbl[(size_t)(rowbase + r)*64 + DTRANK + j];
    }
    float Av[DSTATE];
    #pragma unroll
    for (int s4 = 0; s4 < 4; ++s4){
        float4 a4 = *(const float4*)(A_log + (size_t)d*DSTATE + s4*4);
        Av[s4*4+0] = -__expf(a4.x);
        Av[s4*4+1] = -__expf(a4.y);
        Av[s4*4+2] = -__expf(a4.z);
        Av[s4*4+3] = -__expf(a4.w);
    }
    __syncthreads();
    float h[DSTATE] = {};
    float ds = 0.f;
    for (int tt = 0; tt < LC; ++tt){
        size_t row = (size_t)(rowbase + tt);
        float dlt = delta[row*DINNER + d];
        float uv  = u[row*DINNER + d];
        ds += dlt;
        float du = dlt*uv;
        #pragma unroll
        for (int s = 0; s < DSTATE; ++s)
            h[s] = fmaf(__expf(dlt*Av[s]), h[s], du*bc[tt][s]);
    }
    size_t base = ((size_t)(b*NC + c)*DINNER + d)*DSTATE;
    #pragma unroll
    for (int s4=0;s4<4;s4++)
        *(float4*)(hend + base + s4*4) =
            make_float4(h[s4*4],h[s4*4+1],h[s4*4+2],h[s4*4+3]);
    dsum_out[(size_t)(b*NC+c)*DINNER + d] = ds;
}

__global__ __launch_bounds__(256)
void scan_pass2(const float* __restrict__ hend, const float* __restrict__ dsum,
                const float* __restrict__ A_log, float* __restrict__ hin)
{
    int gid = blockIdx.x*256 + threadIdx.x;
    int s = gid & 15;
    int bd = gid >> 4;
    int d = bd & (DINNER-1);
    int b = bd >> 10;
    float Av = -__expf(A_log[(size_t)d*DSTATE + s]);
    float h = 0.f;
    for (int c = 0; c < NC; ++c){
        size_t idx = ((size_t)(b*NC + c)*DINNER + d)*DSTATE + s;
        hin[idx] = h;
        h = fmaf(__expf(Av*dsum[(size_t)(b*NC+c)*DINNER + d]), h, hend[idx]);
    }
}

// pass3: seeded local scan + y = sum_s h*C, + u*D, * silu(z)  -> bf16 y
__global__ __launch_bounds__(256)
void scan_pass3(const float* __restrict__ delta, const float* __restrict__ u,
                const float* __restrict__ xdbl, const float* __restrict__ xz,
                const float* __restrict__ A_log, const float* __restrict__ D_skip,
                const float* __restrict__ hin, __hip_bfloat16* __restrict__ y)
{
    __shared__ float bc[LC][32];
    int c = blockIdx.x;
    int b = blockIdx.y >> 2, dg = blockIdx.y & 3;
    int t = threadIdx.x;
    int d = dg*256 + t;
    int rowbase = b*SEQ + c*LC;
    for (int idx = t; idx < LC*32; idx += 256){
        int r = idx >> 5, j = idx & 31;
        bc[r][j] = xdbl[(size_t)(rowbase + r)*64 + DTRANK + j];
    }
    float Av[DSTATE];
    #pragma unroll
    for (int s4 = 0; s4 < 4; ++s4){
        float4 a4 = *(const float4*)(A_log + (size_t)d*DSTATE + s4*4);
        Av[s4*4+0] = -__expf(a4.x);
        Av[s4*4+1] = -__expf(a4.y);
        Av[s4*4+2] = -__expf(a4.z);
        Av[s4*4+3] = -__expf(a4.w);
    }
    float h[DSTATE];
    size_t hbase = ((size_t)(b*NC + c)*DINNER + d)*DSTATE;
    #pragma unroll
    for (int s4=0;s4<4;s4++){
        float4 h4 = *(const float4*)(hin + hbase + s4*4);
        h[s4*4+0]=h4.x; h[s4*4+1]=h4.y; h[s4*4+2]=h4.z; h[s4*4+3]=h4.w;
    }
    float Dv = D_skip[d];
    __syncthreads();
    for (int tt = 0; tt < LC; ++tt){
        size_t row = (size_t)(rowbase + tt);
        float dlt = delta[row*DINNER + d];
        float uv  = u[row*DINNER + d];
        float du = dlt*uv;
        float yv = 0.f;
        #pragma unroll
        for (int s = 0; s < DSTATE; ++s){
            h[s] = fmaf(__expf(dlt*Av[s]), h[s], du*bc[tt][s]);
            yv = fmaf(h[s], bc[tt][16+s], yv);
        }
        float zv = xz[row*(2*DINNER) + DINNER + d];
        y[row*DINNER + d] = __float2bfloat16((yv + uv*Dv) * (zv * sigmoidf_(zv)));
    }
}

// ---------------------------------------------------------------- fused cross-attention (bf16 out)
__global__ __launch_bounds__(256)
void attn_kernel(const float* __restrict__ q, const float* __restrict__ k,
                 const float* __restrict__ v, __hip_bfloat16* __restrict__ outp,
                 float* __restrict__ attn_mean)
{
    __shared__ float qs[DIM];
    __shared__ float sc[HEADS][CTX];
    int row = blockIdx.x;
    int b = row >> 10;
    int t = threadIdx.x;
    qs[t]       = q[(size_t)row*DIM + t];
    qs[t+256]   = q[(size_t)row*DIM + t + 256];
    __syncthreads();
    for (int p = t; p < HEADS*CTX; p += 256){
        int h = p / CTX, si = p - h*CTX;
        const float* kp = k + ((size_t)(b*CTX + si))*DIM + h*DH;
        const float* qp = qs + h*DH;
        float acc = 0.f;
        #pragma unroll 8
        for (int i=0;i<DH;i++) acc = fmaf(qp[i], kp[i], acc);
        sc[h][si] = acc * 0.125f;
    }
    __syncthreads();
    int wv = t >> 6, ln = t & 63;
    #pragma unroll
    for (int hh=0; hh<2; ++hh){
        int h = wv*2 + hh;
        float v1 = (ln < CTX) ? sc[h][ln] : -1e30f;
        float v2 = (ln+64 < CTX) ? sc[h][ln+64] : -1e30f;
        float m = fmaxf(v1,v2);
        #pragma unroll
        for (int o=32;o>=1;o>>=1) m = fmaxf(m, __shfl_xor(m,o));
        float e1 = (ln < CTX) ? __expf(v1-m) : 0.f;
        float e2 = (ln+64 < CTX) ? __expf(v2-m) : 0.f;
        float ssum = e1+e2;
        #pragma unroll
        for (int o=32;o>=1;o>>=1) ssum += __shfl_xor(ssum,o);
        float inv = 1.f/ssum;
        if (ln < CTX)    sc[h][ln]    = e1*inv;
        if (ln+64 < CTX) sc[h][ln+64] = e2*inv;
    }
    __syncthreads();
    for (int dim = t; dim < DIM; dim += 256){
        int h = dim >> 6;
        float acc = 0.f;
        for (int si=0; si<CTX; ++si)
            acc = fmaf(sc[h][si], v[((size_t)(b*CTX+si))*DIM + dim], acc);
        outp[(size_t)row*DIM + dim] = __float2bfloat16(acc);
    }
    if (t < CTX){
        float acc = 0.f;
        #pragma unroll
        for (int h=0;h<HEADS;h++) acc += sc[h][t];
        attn_mean[(size_t)row*CTX + t] = acc * (1.f/HEADS);
    }
}

// ---------------------------------------------------------------- launcher
extern "C" void kernel_launch(void* const* d_in, const int* in_sizes, int n_in,
                              void* d_out, int out_size, void* d_ws, size_t ws_size,
                              hipStream_t stream)
{
    (void)in_sizes; (void)n_in; (void)out_size; (void)ws_size;
    const int*   x        = (const int*)  d_in[0];
    const float* context  = (const float*)d_in[1];
    const float* tok_emb  = (const float*)d_in[2];
    const float* pos_emb  = (const float*)d_in[3];
    const float* ln1_g    = (const float*)d_in[4];
    const float* ln1_b    = (const float*)d_in[5];
    const float* in_w     = (const float*)d_in[6];
    const float* conv_w   = (const float*)d_in[7];
    const float* conv_b   = (const float*)d_in[8];
    const float* xproj_w  = (const float*)d_in[9];
    const float* dt_w     = (const float*)d_in[10];
    const float* dt_b     = (const float*)d_in[11];
    const float* A_log    = (const float*)d_in[12];
    const float* D_skip   = (const float*)d_in[13];
    const float* out_w    = (const float*)d_in[14];
    const float* ln2_g    = (const float*)d_in[15];
    const float* ln2_b    = (const float*)d_in[16];
    const float* ain_w    = (const float*)d_in[17];
    const float* ain_b    = (const float*)d_in[18];
    const float* aout_w   = (const float*)d_in[19];
    const float* aout_b   = (const float*)d_in[20];
    const float* lnf_g    = (const float*)d_in[21];
    const float* lnf_b    = (const float*)d_in[22];
    const float* logit_w  = (const float*)d_in[23];
    const float* logit_b  = (const float*)d_in[24];
    float* out = (float*)d_out;

    // ---- workspace (fp32 + bf16 staging), 16.5M floats = 66 MB
    float* ws = (float*)d_ws;
    size_t off = 0;
    float* hbuf  = ws + off;  off += (size_t)NTOK*DIM;        // 2.10M
    float* ubuf  = ws + off;  off += (size_t)NTOK*DINNER;     // 4.19M
    float* qbuf  = ws + off;  off += (size_t)NTOK*DIM;        // 2.10M
    float* xdbl  = ws + off;  off += (size_t)NTOK*64;         // 0.26M
    float* dbuf  = ws + off;  off += (size_t)NTOK*DINNER;     // 4.19M
    __hip_bfloat16* tnorm_bf   = (__hip_bfloat16*)(ws + off); off += (size_t)NTOK*DIM/2;
    __hip_bfloat16* logit_w_bf = (__hip_bfloat16*)(ws + off); off += (size_t)NPAD*DIM/2;
    float* kbuf = dbuf;                       // dead after scan
    float* vbuf = dbuf + 262144;

    // ---- scratch in dead logits region of d_out (<19.8M of 40.96M floats)
    float* ob = out;
    float* xz    = ob;                 ob += (size_t)NTOK*2*DINNER;           // 8.39M
    float* hend  = ob;                 ob += (size_t)BATCH*NC*DINNER*DSTATE;  // 2.10M
    float* hinb  = ob;                 ob += (size_t)BATCH*NC*DINNER*DSTATE;  // 2.10M
    float* dsumb = ob;                 ob += (size_t)BATCH*NC*DINNER;         // 0.13M
    __hip_bfloat16* bfp = (__hip_bfloat16*)ob;
    __hip_bfloat16* in_w_bf   = bfp;   bfp += (size_t)DEPTH*2*DINNER*DIM;     // 3.15M
    __hip_bfloat16* out_w_bf  = bfp;   bfp += (size_t)DEPTH*DIM*DINNER;       // 1.57M
    __hip_bfloat16* ainw_bf   = bfp;   bfp += (size_t)DEPTH*3*DIM*DIM;        // 2.36M
    __hip_bfloat16* aoutw_bf  = bfp;   bfp += (size_t)DEPTH*DIM*DIM;          // 0.79M
    __hip_bfloat16* ybuf_bf   = bfp;   bfp += (size_t)NTOK*DINNER;            // 4.19M
    __hip_bfloat16* abuf_bf   = bfp;   bfp += (size_t)NTOK*DIM;               // 2.10M

    // ---- weight conversions (once per launch)
    f2bf_kernel<<<(DEPTH*2*DINNER*DIM)/2048, 256, 0, stream>>>(in_w, in_w_bf);
    f2bf_kernel<<<(DEPTH*DIM*DINNER)/2048, 256, 0, stream>>>(out_w, out_w_bf);
    f2bf_kernel<<<(DEPTH*3*DIM*DIM)/2048, 256, 0, stream>>>(ain_w, ainw_bf);
    f2bf_kernel<<<(DEPTH*DIM*DIM)/2048, 256, 0, stream>>>(aout_w, aoutw_bf);
    f2bf_kernel<<<(VOCAB*DIM)/2048, 256, 0, stream>>>(logit_w, logit_w_bf);
    hipMemsetAsync(logit_w_bf + (size_t)VOCAB*DIM, 0,
                   (size_t)(NPAD-VOCAB)*DIM*sizeof(__hip_bfloat16), stream);

    embed_kernel<<<NTOK, 128, 0, stream>>>(x, tok_emb, pos_emb, hbuf);

    float* attn_out_base = out + (size_t)NTOK*VOCAB;

    for (int i = 0; i < DEPTH; ++i){
        const float* Ai = A_log + (size_t)i*DINNER*DSTATE;
        layernorm_kernel<<<NTOK, 256, 0, stream>>>(hbuf, ln1_g + i*DIM, ln1_b + i*DIM, tnorm_bf);
        // in_proj: [4096,512]@[2048,512]^T -> xz
        gemm_bf16<0,0,0><<<dim3(2*DINNER/128, NTOK/128), 256, 0, stream>>>(
            tnorm_bf, DIM, in_w_bf + (size_t)i*2*DINNER*DIM, DIM, nullptr,
            xz, 2*DINNER, 2*DINNER, DIM);
        conv_silu_kernel<<<(NTOK*DINNER)/256, 256, 0, stream>>>(
            xz, conv_w + (size_t)i*DINNER*DCONV, conv_b + i*DINNER, ubuf);
        // x_proj (fp32, small N)
        gemm_f32<0,0,0><<<dim3(1, NTOK/64), 256, 0, stream>>>(
            ubuf, DINNER, xproj_w + (size_t)i*64*DINNER, DINNER, nullptr,
            xdbl, 64, NTOK, 64, DINNER);
        // dt_proj + softplus (fp32, K=32)
        gemm_f32<1,1,0><<<dim3(DINNER/64, NTOK/64), 256, 0, stream>>>(
            xdbl, 64, dt_w + (size_t)i*DINNER*DTRANK, DTRANK, dt_b + i*DINNER,
            dbuf, DINNER, NTOK, DINNER, DTRANK);
        // chunked selective scan -> ybuf_bf
        scan_pass1<<<dim3(NC, BATCH*4), 256, 0, stream>>>(
            dbuf, ubuf, xdbl, Ai, hend, dsumb);
        scan_pass2<<<(BATCH*DINNER*DSTATE)/256, 256, 0, stream>>>(
            hend, dsumb, Ai, hinb);
        scan_pass3<<<dim3(NC, BATCH*4), 256, 0, stream>>>(
            dbuf, ubuf, xdbl, xz, Ai, D_skip + i*DINNER, hinb, ybuf_bf);
        // out_proj + residual
        gemm_bf16<0,1,0><<<dim3(DIM/128, NTOK/128), 256, 0, stream>>>(
            ybuf_bf, DINNER, out_w_bf + (size_t)i*DIM*DINNER, DINNER, nullptr,
            hbuf, DIM, DIM, DINNER);
        layernorm_kernel<<<NTOK, 256, 0, stream>>>(hbuf, ln2_g + i*DIM, ln2_b + i*DIM, tnorm_bf);
        // q proj (bf16)
        gemm_bf16<1,0,0><<<dim3(DIM/128, NTOK/128), 256, 0, stream>>>(
            tnorm_bf, DIM, ainw_bf + (size_t)i*3*DIM*DIM, DIM, ain_b + (size_t)i*3*DIM,
            qbuf, DIM, DIM, DIM);
        // k/v proj (fp32, M=392)
        gemm_f32<0,1,0><<<dim3(DIM/64, (BATCH*CTX+63)/64), 256, 0, stream>>>(
            context, DIM, ain_w + (size_t)i*3*DIM*DIM + (size_t)DIM*DIM, DIM,
            ain_b + (size_t)i*3*DIM + DIM, kbuf, DIM, BATCH*CTX, DIM, DIM);
        gemm_f32<0,1,0><<<dim3(DIM/64, (BATCH*CTX+63)/64), 256, 0, stream>>>(
            context, DIM, ain_w + (size_t)i*3*DIM*DIM + (size_t)2*DIM*DIM, DIM,
            ain_b + (size_t)i*3*DIM + 2*DIM, vbuf, DIM, BATCH*CTX, DIM, DIM);
        attn_kernel<<<NTOK, 256, 0, stream>>>(qbuf, kbuf, vbuf, abuf_bf,
            attn_out_base + (size_t)i*NTOK*CTX);
        // attn out proj + residual
        gemm_bf16<1,1,0><<<dim3(DIM/128, NTOK/128), 256, 0, stream>>>(
            abuf_bf, DIM, aoutw_bf + (size_t)i*DIM*DIM, DIM, aout_b + i*DIM,
            hbuf, DIM, DIM, DIM);
    }
    layernorm_kernel<<<NTOK, 256, 0, stream>>>(hbuf, lnf_g, lnf_b, tnorm_bf);
    // logits: N padded to 10240, store-masked to 10000
    gemm_bf16<1,0,1><<<dim3(NPAD/128, NTOK/128), 256, 0, stream>>>(
        tnorm_bf, DIM, logit_w_bf, DIM, logit_b, out, VOCAB, VOCAB, DIM);
}